// Round 10
// baseline (545.180 us; speedup 1.0000x reference)
//
#include <hip/hip_runtime.h>
#include <hip/hip_fp16.h>

#define D 128
#define TM 32    // nodes per block
#define AHP 264  // MFMA A-tile halves/row: 528B, +16B pad -> <=2-way bank alias

typedef float f4v __attribute__((ext_vector_type(4)));
typedef float f2v __attribute__((ext_vector_type(2)));
typedef _Float16 h8v __attribute__((ext_vector_type(8)));

#define Q8_SCALE 16.0f      // fp8 storage scale: |act|*16 << 448 (e4m3 max)
#define Q8_INV   0.0625f

static __device__ __forceinline__ unsigned pkh(float a, float b) {
    __half2 h = __float22half2_rn(make_float2(a, b));
    return *(unsigned*)&h;
}

// ---------------- CSR build ----------------

__global__ void hist_kernel(const int* __restrict__ dst, int* __restrict__ deg, int E) {
    int i = blockIdx.x * blockDim.x + threadIdx.x;
    if (i < E) atomicAdd(&deg[dst[i]], 1);
}

__global__ void scan1_kernel(const int* __restrict__ deg, int* __restrict__ local_excl,
                             int* __restrict__ blocksum, int n) {
    __shared__ int tmp[1024];
    int i = blockIdx.x * 1024 + threadIdx.x;
    int v = (i < n) ? deg[i] : 0;
    tmp[threadIdx.x] = v;
    __syncthreads();
    for (int off = 1; off < 1024; off <<= 1) {
        int t = 0;
        if (threadIdx.x >= off) t = tmp[threadIdx.x - off];
        __syncthreads();
        if (threadIdx.x >= off) tmp[threadIdx.x] += t;
        __syncthreads();
    }
    int incl = tmp[threadIdx.x];
    if (i < n) local_excl[i] = incl - v;
    if (threadIdx.x == 1023) blocksum[blockIdx.x] = tmp[1023];
}

__global__ void scan2_kernel(int* __restrict__ blocksum, int nb) {
    __shared__ int tmp[1024];
    int v = (threadIdx.x < nb) ? blocksum[threadIdx.x] : 0;
    tmp[threadIdx.x] = v;
    __syncthreads();
    for (int off = 1; off < 1024; off <<= 1) {
        int t = 0;
        if (threadIdx.x >= off) t = tmp[threadIdx.x - off];
        __syncthreads();
        if (threadIdx.x >= off) tmp[threadIdx.x] += t;
        __syncthreads();
    }
    if (threadIdx.x < nb) blocksum[threadIdx.x] = tmp[threadIdx.x] - v;  // exclusive
}

__global__ void scan3_kernel(const int* __restrict__ deg, const int* __restrict__ local_excl,
                             const int* __restrict__ blocksum, int* __restrict__ row_start,
                             int* __restrict__ cursor, float* __restrict__ inv_deg,
                             int n, int n_edges) {
    int i = blockIdx.x * 1024 + threadIdx.x;
    if (i < n) {
        int rs = local_excl[i] + blocksum[blockIdx.x];
        row_start[i] = rs;
        cursor[i]    = rs;
        inv_deg[i]   = 1.0f / fmaxf((float)deg[i], 1.0f);
    }
    if (i == 0) row_start[n] = n_edges;
}

// csr[] holds BYTE offsets of the fp8 source row (src * 128).
// r18: XCD-affine scatter -- slot x = blockIdx&7 handles only dst range x,
// so each csr line is written by exactly one XCD L2 (no cross-XCD partial
// dirty lines -> writebacks collapse ~8x). Correctness never depends on
// the %8 dispatch mapping.
__global__ void scatter_kernel(const int* __restrict__ src, const int* __restrict__ dst,
                               int* __restrict__ cursor, int* __restrict__ csr,
                               int E, int npx) {
    int x  = blockIdx.x & 7;
    int lo = x * npx, hi = lo + npx;
    int stride = (gridDim.x >> 3) * blockDim.x;
    for (int i = (blockIdx.x >> 3) * blockDim.x + threadIdx.x; i < E; i += stride) {
        int d = dst[i];
        if (d >= lo && d < hi) {
            int p = atomicAdd(&cursor[d], 1);
            csr[p] = src[i] << 7;
        }
    }
}

// ---------------- MFMA weight prepack ----------------
// Fragment-order fp16 pack for mfma_f32_16x16x32_f16, swapped-operand use:
// A-operand = weight tile, lane l holds row f = ft*16+(l&15),
// k = ks*32 + (l>>4)*8 + j (j=0..7). K-concat: ks 0..3 -> Wl (agg path),
// ks 4..7 -> Wr (x path). One fragment = 64 consecutive uint4 = 1KB
// contiguous -> frag loads in the layer kernel are coalesced dwordx4.
__global__ void prepack_w(const float* __restrict__ Wl, const float* __restrict__ Wr,
                          __half* __restrict__ wpack, int total) {
    int t = blockIdx.x * blockDim.x + threadIdx.x;   // ((l*8+ft)*8+ks)*64+lane
    if (t >= total) return;
    int lane = t & 63;
    int ks   = (t >> 6) & 7;
    int ft   = (t >> 9) & 7;
    int l    = t >> 12;
    int f = ft * 16 + (lane & 15);
    int k = (ks & 3) * 32 + ((lane >> 4) << 3);
    const float* W = (ks < 4) ? Wl : Wr;
    const float* src = W + ((size_t)l << 14) + ((size_t)f << 7) + k;
    float4 v0 = *(const float4*)src;
    float4 v1 = *(const float4*)(src + 4);
    uint4 u = {pkh(v0.x, v0.y), pkh(v0.z, v0.w), pkh(v1.x, v1.y), pkh(v1.z, v1.w)};
    ((uint4*)wpack)[t] = u;
}

// ---------------- initial fp32 -> fp8 + fp16 shadow copies ----------------

__global__ void x_to_shadow(const float* __restrict__ x, unsigned* __restrict__ xq,
                            uint2* __restrict__ xh, int total4) {
    int i = blockIdx.x * blockDim.x + threadIdx.x;
    if (i < total4) {
        float4 v = ((const float4*)x)[i];
        unsigned u = 0;
        u = __builtin_amdgcn_cvt_pk_fp8_f32(v.x * Q8_SCALE, v.y * Q8_SCALE, u, false);
        u = __builtin_amdgcn_cvt_pk_fp8_f32(v.z * Q8_SCALE, v.w * Q8_SCALE, u, true);
        xq[i] = u;
        uint2 h = {pkh(v.x, v.y), pkh(v.z, v.w)};
        xh[i] = h;
    }
}

// ---------------- gather helpers ----------------

#define ACC16Q(V) {                                                          \
    f2v a0_ = __builtin_amdgcn_cvt_pk_f32_fp8((int)(V).x, false);            \
    f2v a1_ = __builtin_amdgcn_cvt_pk_f32_fp8((int)(V).x, true);             \
    f2v b0_ = __builtin_amdgcn_cvt_pk_f32_fp8((int)(V).y, false);            \
    f2v b1_ = __builtin_amdgcn_cvt_pk_f32_fp8((int)(V).y, true);             \
    f2v c0_ = __builtin_amdgcn_cvt_pk_f32_fp8((int)(V).z, false);            \
    f2v c1_ = __builtin_amdgcn_cvt_pk_f32_fp8((int)(V).z, true);             \
    f2v d0_ = __builtin_amdgcn_cvt_pk_f32_fp8((int)(V).w, false);            \
    f2v d1_ = __builtin_amdgcn_cvt_pk_f32_fp8((int)(V).w, true);             \
    s0.x += a0_.x; s0.y += a0_.y; s0.z += a1_.x; s0.w += a1_.y;              \
    s1.x += b0_.x; s1.y += b0_.y; s1.z += b1_.x; s1.w += b1_.y;              \
    s2.x += c0_.x; s2.y += c0_.y; s2.z += c1_.x; s2.w += c1_.y;              \
    s3.x += d0_.x; s3.y += d0_.y; s3.z += d1_.x; s3.w += d1_.y; }

#define ACC8(V) { const __half2* hp_ = (const __half2*)&(V);                 \
    float2 f0_ = __half22float2(hp_[0]); float2 f1_ = __half22float2(hp_[1]);\
    float2 f2_ = __half22float2(hp_[2]); float2 f3_ = __half22float2(hp_[3]);\
    sA.x += f0_.x; sA.y += f0_.y; sA.z += f1_.x; sA.w += f1_.y;              \
    sB.x += f2_.x; sB.y += f2_.y; sB.z += f3_.x; sB.w += f3_.y; }

// ---------------- MFMA fused SAGE layer ----------------
// r19: the fp32 inter-layer round-trip is deleted. r18 post-mortem: layers
// are BW-bound (3.46 TB/s, FETCH 203MB = gather ~140 + fp32-xin 51.2 +
// csr 6.4; WRITE 70 = fp32-xout 51.2 + shadows). But the next layer only
// ever consumes fp16(xout) -- converting at the epilogue (store fp16) is
// bit-identical to converting at the next X-fill. So layers 0..2 write
// shadows only; X-fill reads the fp16 shadow (25.6MB, cache-hot, no nt);
// only l3 writes fp32. -51.2MB/layer, zero numerical change.
// launch_bounds (256,8): VGPR 48 fits <=64, allows 8 blocks/CU for gather
// latency hiding (occupancy was 45%).
// INFMT: 0 = gather fp8 rows (128B), 1 = gather fp16 rows (256B).
// OUTFMT: 0 = write fp8+fp16 shadows, 1 = fp16 shadow only, 2 = fp32 final.
template<int INFMT, int OUTFMT>
__global__ __launch_bounds__(256, 8)
void sage_layer_mfma(const __half* __restrict__ xh_in,
                     const void* __restrict__ xq_in,
                     float* __restrict__ xout,
                     unsigned* __restrict__ q8_out,
                     uint2* __restrict__ h16_out,
                     const int* __restrict__ row_start, const int* __restrict__ csr,
                     const float* __restrict__ inv_deg,
                     const __half* __restrict__ wpack,
                     const float* __restrict__ bl, int n_nodes) {
    __shared__ __align__(16) __half Ah[TM][AHP];
    int block0 = blockIdx.x * TM;
    int tid = threadIdx.x;
    int lane = tid & 63;
    int wv   = tid >> 6;

    // X-fill: fp16 shadow rows -> columns 128..255 of A-tile (pure copy,
    // cache-hot source: written by the previous layer).
    {
        int row = tid >> 3;          // 0..31
        int seg = tid & 7;           // 16 halves per thread
        int nn = block0 + row;
        uint4 a = {0,0,0,0}, b = a;
        if (nn < n_nodes) {
            const uint4* hp = (const uint4*)(xh_in + (size_t)nn * D) + seg * 2;
            a = hp[0];
            b = hp[1];
        }
        uint4* dst = (uint4*)&Ah[row][128 + seg * 16];
        dst[0] = a; dst[1] = b;
    }

    // Phase A: gather -> fp32 acc -> fp16 into columns 0..127 of A-tile.
    if constexpr (INFMT == 0) {
        // fp8: 8-lane group per node, 32 concurrent nodes, 4-deep pipeline.
        int g   = tid >> 3;       // 0..31
        int sub = tid & 7;
        int n = block0 + g;
        float4 s0 = {0,0,0,0}, s1 = {0,0,0,0}, s2 = {0,0,0,0}, s3 = {0,0,0,0};
        float idg = 1.f;
        int e0 = 0, e1 = 0;
        if (n < n_nodes) {
            e0 = row_start[n];
            e1 = row_start[n + 1];
            idg = inv_deg[n];
        }
        int e = e0;
        if (e < e1) {
            int last = e1 - 1;
            const char* qbase = (const char*)xq_in;
            int laneoff = sub * 16;
            int i0 = csr[min(e,     last)];
            int i1 = csr[min(e + 1, last)];
            int i2 = csr[min(e + 2, last)];
            int i3 = csr[min(e + 3, last)];
            while (1) {
                uint4 v0 = *(const uint4*)(qbase + (size_t)(i0 + laneoff));
                uint4 v1 = *(const uint4*)(qbase + (size_t)(i1 + laneoff));
                uint4 v2 = *(const uint4*)(qbase + (size_t)(i2 + laneoff));
                uint4 v3 = *(const uint4*)(qbase + (size_t)(i3 + laneoff));
                int en = e + 4;
                bool more = en < e1;
                int p0, p1, p2, p3;
                if (more) {
                    p0 = csr[min(en,     last)];
                    p1 = csr[min(en + 1, last)];
                    p2 = csr[min(en + 2, last)];
                    p3 = csr[min(en + 3, last)];
                }
                ACC16Q(v0)
                if (e + 1 <= last) ACC16Q(v1)
                if (e + 2 <= last) ACC16Q(v2)
                if (e + 3 <= last) ACC16Q(v3)
                if (!more) break;
                e = en;
                i0 = p0; i1 = p1; i2 = p2; i3 = p3;
            }
        }
        float sc = idg * Q8_INV;
        uint4 ua = {pkh(s0.x*sc,s0.y*sc), pkh(s0.z*sc,s0.w*sc),
                    pkh(s1.x*sc,s1.y*sc), pkh(s1.z*sc,s1.w*sc)};
        uint4 ub = {pkh(s2.x*sc,s2.y*sc), pkh(s2.z*sc,s2.w*sc),
                    pkh(s3.x*sc,s3.y*sc), pkh(s3.z*sc,s3.w*sc)};
        uint4* dst = (uint4*)&Ah[g][sub * 16];
        dst[0] = ua; dst[1] = ub;
    } else {
        // fp16: 16-lane group per node, 2 sequential nodes per group.
        int g   = tid >> 4;       // 0..15
        int sub = tid & 15;
        const char* hbase = (const char*)xq_in;
        int laneoff = sub * 16;   // 16B per lane within 256B fp16 row
        for (int t = 0; t < 2; ++t) {
            int j = g + t * 16;
            int n = block0 + j;
            float4 sA = {0,0,0,0}, sB = {0,0,0,0};
            float idg = 1.f;
            int e0 = 0, e1 = 0;
            if (n < n_nodes) {
                e0 = row_start[n];
                e1 = row_start[n + 1];
                idg = inv_deg[n];
            }
            int e = e0;
            if (e < e1) {
                int last = e1 - 1;
                int i0 = csr[min(e,     last)] << 1;
                int i1 = csr[min(e + 1, last)] << 1;
                int i2 = csr[min(e + 2, last)] << 1;
                int i3 = csr[min(e + 3, last)] << 1;
                while (1) {
                    float4 v0 = *(const float4*)(hbase + (size_t)(i0 + laneoff));
                    float4 v1 = *(const float4*)(hbase + (size_t)(i1 + laneoff));
                    float4 v2 = *(const float4*)(hbase + (size_t)(i2 + laneoff));
                    float4 v3 = *(const float4*)(hbase + (size_t)(i3 + laneoff));
                    int en = e + 4;
                    bool more = en < e1;
                    int p0, p1, p2, p3;
                    if (more) {
                        p0 = csr[min(en,     last)] << 1;
                        p1 = csr[min(en + 1, last)] << 1;
                        p2 = csr[min(en + 2, last)] << 1;
                        p3 = csr[min(en + 3, last)] << 1;
                    }
                    ACC8(v0)
                    if (e + 1 <= last) ACC8(v1)
                    if (e + 2 <= last) ACC8(v2)
                    if (e + 3 <= last) ACC8(v3)
                    if (!more) break;
                    e = en;
                    i0 = p0; i1 = p1; i2 = p2; i3 = p3;
                }
            }
            uint4 u = {pkh(sA.x*idg, sA.y*idg), pkh(sA.z*idg, sA.w*idg),
                       pkh(sB.x*idg, sB.y*idg), pkh(sB.z*idg, sB.w*idg)};
            *(uint4*)&Ah[j][sub * 8] = u;
        }
    }

    // Preload this wave's 16 weight fragments (2 f-tiles x 8 k-steps),
    // each a unique-data coalesced 1KB dwordx4. L2-hot after block 0.
    uint4 wf[16];
    {
        const uint4* wp = (const uint4*)wpack;
        #pragma unroll
        for (int i = 0; i < 16; ++i) {
            int ft = wv * 2 + (i >> 3);
            int ks = i & 7;
            wf[i] = wp[(size_t)(ft * 8 + ks) * 64 + lane];
        }
    }

    __syncthreads();

    // Phase B: wave wv owns feature tiles {2wv, 2wv+1} x node tiles {0,1}.
    {
        f4v acc[2][2];
        #pragma unroll
        for (int ft = 0; ft < 2; ++ft) {
            int f0 = wv * 32 + ft * 16 + ((lane >> 4) << 2);
            f4v bv = *(const f4v*)(bl + f0);
            acc[ft][0] = bv;
            acc[ft][1] = bv;
        }
        #pragma unroll
        for (int ks = 0; ks < 8; ++ks) {
            int koff = ks * 32 + ((lane >> 4) << 3);
            h8v b0 = *(const h8v*)&Ah[lane & 15][koff];
            h8v b1 = *(const h8v*)&Ah[16 + (lane & 15)][koff];
            h8v a0 = *(const h8v*)&wf[ks];
            h8v a1 = *(const h8v*)&wf[8 + ks];
            acc[0][0] = __builtin_amdgcn_mfma_f32_16x16x32_f16(a0, b0, acc[0][0], 0, 0, 0);
            acc[0][1] = __builtin_amdgcn_mfma_f32_16x16x32_f16(a0, b1, acc[0][1], 0, 0, 0);
            acc[1][0] = __builtin_amdgcn_mfma_f32_16x16x32_f16(a1, b0, acc[1][0], 0, 0, 0);
            acc[1][1] = __builtin_amdgcn_mfma_f32_16x16x32_f16(a1, b1, acc[1][1], 0, 0, 0);
        }
        // Epilogue: lane holds 4 consecutive feats of node (lane&15) per tile.
        #pragma unroll
        for (int ft = 0; ft < 2; ++ft) {
            #pragma unroll
            for (int nt = 0; nt < 2; ++nt) {
                int node = block0 + nt * 16 + (lane & 15);
                int f0 = wv * 32 + ft * 16 + ((lane >> 4) << 2);
                f4v r = acc[ft][nt];
                r.x = fmaxf(r.x, 0.f); r.y = fmaxf(r.y, 0.f);
                r.z = fmaxf(r.z, 0.f); r.w = fmaxf(r.w, 0.f);
                if (node < n_nodes) {
                    if constexpr (OUTFMT == 2) {
                        __builtin_nontemporal_store(r, (f4v*)(xout + (size_t)node * D + f0));
                    } else {
                        uint2 hu = {pkh(r.x, r.y), pkh(r.z, r.w)};
                        h16_out[(size_t)node * 32 + (f0 >> 2)] = hu;
                        if constexpr (OUTFMT == 0) {
                            unsigned u = 0;
                            u = __builtin_amdgcn_cvt_pk_fp8_f32(r.x * Q8_SCALE, r.y * Q8_SCALE, u, false);
                            u = __builtin_amdgcn_cvt_pk_fp8_f32(r.z * Q8_SCALE, r.w * Q8_SCALE, u, true);
                            q8_out[(size_t)node * 32 + (f0 >> 2)] = u;
                        }
                    }
                }
            }
        }
    }
}

extern "C" void kernel_launch(void* const* d_in, const int* in_sizes, int n_in,
                              void* d_out, int out_size, void* d_ws, size_t ws_size,
                              hipStream_t stream) {
    const float* x  = (const float*)d_in[0];
    const int*  edge = (const int*)d_in[1];
    const float* Wl = (const float*)d_in[2];
    const float* bl = (const float*)d_in[3];
    const float* Wr = (const float*)d_in[4];

    int N = in_sizes[0] / D;
    int E = in_sizes[1] / 2;
    int L = in_sizes[3] / D;   // 4
    const int* srcp = edge;
    const int* dstp = edge + E;

    char* w = (char*)d_ws;
    auto alloc = [&](size_t bytes) {
        char* p = w;
        w += (bytes + 255) & ~(size_t)255;
        return p;
    };
    int*   deg       = (int*)alloc((size_t)N * 4);
    int*   local_ex  = (int*)alloc((size_t)N * 4);
    int*   row_start = (int*)alloc((size_t)(N + 1) * 4);
    int*   cursor    = (int*)alloc((size_t)N * 4);
    int*   csr       = (int*)alloc((size_t)E * 4);
    float* invdeg    = (float*)alloc((size_t)N * 4);
    int*   blocksum  = (int*)alloc((size_t)1024 * 4);
    __half* wpack    = (__half*)alloc((size_t)L * 32768 * 2);   // 64KB/layer
    unsigned* q0     = (unsigned*)alloc((size_t)N * D);         // fp8 rows
    unsigned* q1     = (unsigned*)alloc((size_t)N * D);         // fp8 rows
    __half* h0       = (__half*)alloc((size_t)N * D * 2);       // fp16 rows
    __half* h1       = (__half*)alloc((size_t)N * D * 2);       // fp16 rows

    int nb1 = (N + 1023) / 1024;
    hipMemsetAsync(deg, 0, (size_t)N * 4, stream);
    hist_kernel<<<(E + 255) / 256, 256, 0, stream>>>(dstp, deg, E);
    scan1_kernel<<<nb1, 1024, 0, stream>>>(deg, local_ex, blocksum, N);
    scan2_kernel<<<1, 1024, 0, stream>>>(blocksum, nb1);
    scan3_kernel<<<nb1, 1024, 0, stream>>>(deg, local_ex, blocksum, row_start,
                                           cursor, invdeg, N, E);
    int npx = (N + 7) / 8;
    scatter_kernel<<<2048, 256, 0, stream>>>(srcp, dstp, cursor, csr, E, npx);
    int tp = L * 4096;
    prepack_w<<<(tp + 255) / 256, 256, 0, stream>>>(Wl, Wr, wpack, tp);
    int t4 = N * (D / 4);
    x_to_shadow<<<(t4 + 255) / 256, 256, 0, stream>>>(x, q0, (uint2*)h0, t4);

    float* out = (float*)d_out;
    int nbl = (N + TM - 1) / TM;

    // l0: gather fp8 q0, X-fill h0 -> write q1 + h1
    sage_layer_mfma<0, 0><<<nbl, 256, 0, stream>>>(h0, q0, nullptr, q1, (uint2*)h1,
                                                   row_start, csr, invdeg,
                                                   wpack + 0 * 32768, bl + 0 * D, N);
    // l1: gather fp8 q1, X-fill h1 -> write q0 + h0
    sage_layer_mfma<0, 0><<<nbl, 256, 0, stream>>>(h1, q1, nullptr, q0, (uint2*)h0,
                                                   row_start, csr, invdeg,
                                                   wpack + 1 * 32768, bl + 1 * D, N);
    // l2: gather fp8 q0, X-fill h0 -> write h1 only (l3 gathers+X-fills fp16)
    sage_layer_mfma<0, 1><<<nbl, 256, 0, stream>>>(h0, q0, nullptr, nullptr, (uint2*)h1,
                                                   row_start, csr, invdeg,
                                                   wpack + 2 * 32768, bl + 2 * D, N);
    // l3: gather fp16 h1, X-fill h1 -> write fp32 out (final)
    sage_layer_mfma<1, 2><<<nbl, 256, 0, stream>>>(h1, h1, out, nullptr, nullptr,
                                                   row_start, csr, invdeg,
                                                   wpack + 3 * 32768, bl + 3 * D, N);
}

// Round 11
// 465.770 us; speedup vs baseline: 1.1705x; 1.1705x over previous
//
#include <hip/hip_runtime.h>
#include <hip/hip_fp16.h>

#define D 128
#define TM 32    // nodes per block
#define AHP 264  // MFMA A-tile halves/row: 528B, +16B pad -> <=2-way bank alias

typedef float f4v __attribute__((ext_vector_type(4)));
typedef float f2v __attribute__((ext_vector_type(2)));
typedef _Float16 h8v __attribute__((ext_vector_type(8)));

#define Q8_SCALE 16.0f      // fp8 storage scale: |act|*16 << 448 (e4m3 max)
#define Q8_INV   0.0625f

static __device__ __forceinline__ unsigned pkh(float a, float b) {
    __half2 h = __float22half2_rn(make_float2(a, b));
    return *(unsigned*)&h;
}

// ---------------- CSR build ----------------

__global__ void hist_kernel(const int* __restrict__ dst, int* __restrict__ deg, int E) {
    int i = blockIdx.x * blockDim.x + threadIdx.x;
    if (i < E) atomicAdd(&deg[dst[i]], 1);
}

__global__ void scan1_kernel(const int* __restrict__ deg, int* __restrict__ local_excl,
                             int* __restrict__ blocksum, int n) {
    __shared__ int tmp[1024];
    int i = blockIdx.x * 1024 + threadIdx.x;
    int v = (i < n) ? deg[i] : 0;
    tmp[threadIdx.x] = v;
    __syncthreads();
    for (int off = 1; off < 1024; off <<= 1) {
        int t = 0;
        if (threadIdx.x >= off) t = tmp[threadIdx.x - off];
        __syncthreads();
        if (threadIdx.x >= off) tmp[threadIdx.x] += t;
        __syncthreads();
    }
    int incl = tmp[threadIdx.x];
    if (i < n) local_excl[i] = incl - v;
    if (threadIdx.x == 1023) blocksum[blockIdx.x] = tmp[1023];
}

__global__ void scan2_kernel(int* __restrict__ blocksum, int nb) {
    __shared__ int tmp[1024];
    int v = (threadIdx.x < nb) ? blocksum[threadIdx.x] : 0;
    tmp[threadIdx.x] = v;
    __syncthreads();
    for (int off = 1; off < 1024; off <<= 1) {
        int t = 0;
        if (threadIdx.x >= off) t = tmp[threadIdx.x - off];
        __syncthreads();
        if (threadIdx.x >= off) tmp[threadIdx.x] += t;
        __syncthreads();
    }
    if (threadIdx.x < nb) blocksum[threadIdx.x] = tmp[threadIdx.x] - v;  // exclusive
}

__global__ void scan3_kernel(const int* __restrict__ deg, const int* __restrict__ local_excl,
                             const int* __restrict__ blocksum, int* __restrict__ row_start,
                             int* __restrict__ cursor, float* __restrict__ inv_deg,
                             int n, int n_edges) {
    int i = blockIdx.x * 1024 + threadIdx.x;
    if (i < n) {
        int rs = local_excl[i] + blocksum[blockIdx.x];
        row_start[i] = rs;
        cursor[i]    = rs;
        inv_deg[i]   = 1.0f / fmaxf((float)deg[i], 1.0f);
    }
    if (i == 0) row_start[n] = n_edges;
}

// csr[] holds BYTE offsets of the fp8 source row (src * 128).
// r18: XCD-affine scatter -- slot x = blockIdx&7 handles only dst range x,
// so each csr line is written by exactly one XCD L2 (no cross-XCD partial
// dirty lines -> writebacks collapse ~8x). Correctness never depends on
// the %8 dispatch mapping.
__global__ void scatter_kernel(const int* __restrict__ src, const int* __restrict__ dst,
                               int* __restrict__ cursor, int* __restrict__ csr,
                               int E, int npx) {
    int x  = blockIdx.x & 7;
    int lo = x * npx, hi = lo + npx;
    int stride = (gridDim.x >> 3) * blockDim.x;
    for (int i = (blockIdx.x >> 3) * blockDim.x + threadIdx.x; i < E; i += stride) {
        int d = dst[i];
        if (d >= lo && d < hi) {
            int p = atomicAdd(&cursor[d], 1);
            csr[p] = src[i] << 7;
        }
    }
}

// ---------------- MFMA weight prepack ----------------
// Fragment-order fp16 pack for mfma_f32_16x16x32_f16, swapped-operand use:
// A-operand = weight tile, lane l holds row f = ft*16+(l&15),
// k = ks*32 + (l>>4)*8 + j (j=0..7). K-concat: ks 0..3 -> Wl (agg path),
// ks 4..7 -> Wr (x path). One fragment = 64 consecutive uint4 = 1KB
// contiguous -> frag loads in the layer kernel are coalesced dwordx4.
__global__ void prepack_w(const float* __restrict__ Wl, const float* __restrict__ Wr,
                          __half* __restrict__ wpack, int total) {
    int t = blockIdx.x * blockDim.x + threadIdx.x;   // ((l*8+ft)*8+ks)*64+lane
    if (t >= total) return;
    int lane = t & 63;
    int ks   = (t >> 6) & 7;
    int ft   = (t >> 9) & 7;
    int l    = t >> 12;
    int f = ft * 16 + (lane & 15);
    int k = (ks & 3) * 32 + ((lane >> 4) << 3);
    const float* W = (ks < 4) ? Wl : Wr;
    const float* src = W + ((size_t)l << 14) + ((size_t)f << 7) + k;
    float4 v0 = *(const float4*)src;
    float4 v1 = *(const float4*)(src + 4);
    uint4 u = {pkh(v0.x, v0.y), pkh(v0.z, v0.w), pkh(v1.x, v1.y), pkh(v1.z, v1.w)};
    ((uint4*)wpack)[t] = u;
}

// ---------------- initial fp32 -> fp8 + fp16 shadow copies ----------------

__global__ void x_to_shadow(const float* __restrict__ x, unsigned* __restrict__ xq,
                            uint2* __restrict__ xh, int total4) {
    int i = blockIdx.x * blockDim.x + threadIdx.x;
    if (i < total4) {
        float4 v = ((const float4*)x)[i];
        unsigned u = 0;
        u = __builtin_amdgcn_cvt_pk_fp8_f32(v.x * Q8_SCALE, v.y * Q8_SCALE, u, false);
        u = __builtin_amdgcn_cvt_pk_fp8_f32(v.z * Q8_SCALE, v.w * Q8_SCALE, u, true);
        xq[i] = u;
        uint2 h = {pkh(v.x, v.y), pkh(v.z, v.w)};
        xh[i] = h;
    }
}

// ---------------- gather helpers ----------------

#define ACC16Q(V) {                                                          \
    f2v a0_ = __builtin_amdgcn_cvt_pk_f32_fp8((int)(V).x, false);            \
    f2v a1_ = __builtin_amdgcn_cvt_pk_f32_fp8((int)(V).x, true);             \
    f2v b0_ = __builtin_amdgcn_cvt_pk_f32_fp8((int)(V).y, false);            \
    f2v b1_ = __builtin_amdgcn_cvt_pk_f32_fp8((int)(V).y, true);             \
    f2v c0_ = __builtin_amdgcn_cvt_pk_f32_fp8((int)(V).z, false);            \
    f2v c1_ = __builtin_amdgcn_cvt_pk_f32_fp8((int)(V).z, true);             \
    f2v d0_ = __builtin_amdgcn_cvt_pk_f32_fp8((int)(V).w, false);            \
    f2v d1_ = __builtin_amdgcn_cvt_pk_f32_fp8((int)(V).w, true);             \
    s0.x += a0_.x; s0.y += a0_.y; s0.z += a1_.x; s0.w += a1_.y;              \
    s1.x += b0_.x; s1.y += b0_.y; s1.z += b1_.x; s1.w += b1_.y;              \
    s2.x += c0_.x; s2.y += c0_.y; s2.z += c1_.x; s2.w += c1_.y;              \
    s3.x += d0_.x; s3.y += d0_.y; s3.z += d1_.x; s3.w += d1_.y; }

#define ACC8(V) { const __half2* hp_ = (const __half2*)&(V);                 \
    float2 f0_ = __half22float2(hp_[0]); float2 f1_ = __half22float2(hp_[1]);\
    float2 f2_ = __half22float2(hp_[2]); float2 f3_ = __half22float2(hp_[3]);\
    sA.x += f0_.x; sA.y += f0_.y; sA.z += f1_.x; sA.w += f1_.y;              \
    sB.x += f2_.x; sB.y += f2_.y; sB.z += f3_.x; sB.w += f3_.y; }

// ---------------- MFMA fused SAGE layer ----------------
// r20: r19's shadow-only dataflow (fp32 inter-layer round-trip deleted;
// layers 0..2 write fp8/fp16 shadows only, X-fill reads the cache-hot fp16
// shadow; only l3 writes fp32) with the launch_bounds REVERTED to (256,4).
// r19 post-mortem: (256,8) squeezed VGPR 48->32, spilling the 16-uint4
// weight preload to scratch -- WRITE_SIZE 70->148MB (spill stores), FETCH
// +30MB (reloads), layer 81->94us despite occupancy 45->66%. Guideline-6
// violation: bought waves with scratch traffic on a BW-bound kernel.
// INFMT: 0 = gather fp8 rows (128B), 1 = gather fp16 rows (256B).
// OUTFMT: 0 = write fp8+fp16 shadows, 1 = fp16 shadow only, 2 = fp32 final.
template<int INFMT, int OUTFMT>
__global__ __launch_bounds__(256, 4)
void sage_layer_mfma(const __half* __restrict__ xh_in,
                     const void* __restrict__ xq_in,
                     float* __restrict__ xout,
                     unsigned* __restrict__ q8_out,
                     uint2* __restrict__ h16_out,
                     const int* __restrict__ row_start, const int* __restrict__ csr,
                     const float* __restrict__ inv_deg,
                     const __half* __restrict__ wpack,
                     const float* __restrict__ bl, int n_nodes) {
    __shared__ __align__(16) __half Ah[TM][AHP];
    int block0 = blockIdx.x * TM;
    int tid = threadIdx.x;
    int lane = tid & 63;
    int wv   = tid >> 6;

    // X-fill: fp16 shadow rows -> columns 128..255 of A-tile (pure copy,
    // cache-hot source: written by the previous layer).
    {
        int row = tid >> 3;          // 0..31
        int seg = tid & 7;           // 16 halves per thread
        int nn = block0 + row;
        uint4 a = {0,0,0,0}, b = a;
        if (nn < n_nodes) {
            const uint4* hp = (const uint4*)(xh_in + (size_t)nn * D) + seg * 2;
            a = hp[0];
            b = hp[1];
        }
        uint4* dst = (uint4*)&Ah[row][128 + seg * 16];
        dst[0] = a; dst[1] = b;
    }

    // Phase A: gather -> fp32 acc -> fp16 into columns 0..127 of A-tile.
    if constexpr (INFMT == 0) {
        // fp8: 8-lane group per node, 32 concurrent nodes, 4-deep pipeline.
        int g   = tid >> 3;       // 0..31
        int sub = tid & 7;
        int n = block0 + g;
        float4 s0 = {0,0,0,0}, s1 = {0,0,0,0}, s2 = {0,0,0,0}, s3 = {0,0,0,0};
        float idg = 1.f;
        int e0 = 0, e1 = 0;
        if (n < n_nodes) {
            e0 = row_start[n];
            e1 = row_start[n + 1];
            idg = inv_deg[n];
        }
        int e = e0;
        if (e < e1) {
            int last = e1 - 1;
            const char* qbase = (const char*)xq_in;
            int laneoff = sub * 16;
            int i0 = csr[min(e,     last)];
            int i1 = csr[min(e + 1, last)];
            int i2 = csr[min(e + 2, last)];
            int i3 = csr[min(e + 3, last)];
            while (1) {
                uint4 v0 = *(const uint4*)(qbase + (size_t)(i0 + laneoff));
                uint4 v1 = *(const uint4*)(qbase + (size_t)(i1 + laneoff));
                uint4 v2 = *(const uint4*)(qbase + (size_t)(i2 + laneoff));
                uint4 v3 = *(const uint4*)(qbase + (size_t)(i3 + laneoff));
                int en = e + 4;
                bool more = en < e1;
                int p0, p1, p2, p3;
                if (more) {
                    p0 = csr[min(en,     last)];
                    p1 = csr[min(en + 1, last)];
                    p2 = csr[min(en + 2, last)];
                    p3 = csr[min(en + 3, last)];
                }
                ACC16Q(v0)
                if (e + 1 <= last) ACC16Q(v1)
                if (e + 2 <= last) ACC16Q(v2)
                if (e + 3 <= last) ACC16Q(v3)
                if (!more) break;
                e = en;
                i0 = p0; i1 = p1; i2 = p2; i3 = p3;
            }
        }
        float sc = idg * Q8_INV;
        uint4 ua = {pkh(s0.x*sc,s0.y*sc), pkh(s0.z*sc,s0.w*sc),
                    pkh(s1.x*sc,s1.y*sc), pkh(s1.z*sc,s1.w*sc)};
        uint4 ub = {pkh(s2.x*sc,s2.y*sc), pkh(s2.z*sc,s2.w*sc),
                    pkh(s3.x*sc,s3.y*sc), pkh(s3.z*sc,s3.w*sc)};
        uint4* dst = (uint4*)&Ah[g][sub * 16];
        dst[0] = ua; dst[1] = ub;
    } else {
        // fp16: 16-lane group per node, 2 sequential nodes per group.
        int g   = tid >> 4;       // 0..15
        int sub = tid & 15;
        const char* hbase = (const char*)xq_in;
        int laneoff = sub * 16;   // 16B per lane within 256B fp16 row
        for (int t = 0; t < 2; ++t) {
            int j = g + t * 16;
            int n = block0 + j;
            float4 sA = {0,0,0,0}, sB = {0,0,0,0};
            float idg = 1.f;
            int e0 = 0, e1 = 0;
            if (n < n_nodes) {
                e0 = row_start[n];
                e1 = row_start[n + 1];
                idg = inv_deg[n];
            }
            int e = e0;
            if (e < e1) {
                int last = e1 - 1;
                int i0 = csr[min(e,     last)] << 1;
                int i1 = csr[min(e + 1, last)] << 1;
                int i2 = csr[min(e + 2, last)] << 1;
                int i3 = csr[min(e + 3, last)] << 1;
                while (1) {
                    float4 v0 = *(const float4*)(hbase + (size_t)(i0 + laneoff));
                    float4 v1 = *(const float4*)(hbase + (size_t)(i1 + laneoff));
                    float4 v2 = *(const float4*)(hbase + (size_t)(i2 + laneoff));
                    float4 v3 = *(const float4*)(hbase + (size_t)(i3 + laneoff));
                    int en = e + 4;
                    bool more = en < e1;
                    int p0, p1, p2, p3;
                    if (more) {
                        p0 = csr[min(en,     last)] << 1;
                        p1 = csr[min(en + 1, last)] << 1;
                        p2 = csr[min(en + 2, last)] << 1;
                        p3 = csr[min(en + 3, last)] << 1;
                    }
                    ACC8(v0)
                    if (e + 1 <= last) ACC8(v1)
                    if (e + 2 <= last) ACC8(v2)
                    if (e + 3 <= last) ACC8(v3)
                    if (!more) break;
                    e = en;
                    i0 = p0; i1 = p1; i2 = p2; i3 = p3;
                }
            }
            uint4 u = {pkh(sA.x*idg, sA.y*idg), pkh(sA.z*idg, sA.w*idg),
                       pkh(sB.x*idg, sB.y*idg), pkh(sB.z*idg, sB.w*idg)};
            *(uint4*)&Ah[j][sub * 8] = u;
        }
    }

    // Preload this wave's 16 weight fragments (2 f-tiles x 8 k-steps),
    // each a unique-data coalesced 1KB dwordx4. L2-hot after block 0.
    uint4 wf[16];
    {
        const uint4* wp = (const uint4*)wpack;
        #pragma unroll
        for (int i = 0; i < 16; ++i) {
            int ft = wv * 2 + (i >> 3);
            int ks = i & 7;
            wf[i] = wp[(size_t)(ft * 8 + ks) * 64 + lane];
        }
    }

    __syncthreads();

    // Phase B: wave wv owns feature tiles {2wv, 2wv+1} x node tiles {0,1}.
    {
        f4v acc[2][2];
        #pragma unroll
        for (int ft = 0; ft < 2; ++ft) {
            int f0 = wv * 32 + ft * 16 + ((lane >> 4) << 2);
            f4v bv = *(const f4v*)(bl + f0);
            acc[ft][0] = bv;
            acc[ft][1] = bv;
        }
        #pragma unroll
        for (int ks = 0; ks < 8; ++ks) {
            int koff = ks * 32 + ((lane >> 4) << 3);
            h8v b0 = *(const h8v*)&Ah[lane & 15][koff];
            h8v b1 = *(const h8v*)&Ah[16 + (lane & 15)][koff];
            h8v a0 = *(const h8v*)&wf[ks];
            h8v a1 = *(const h8v*)&wf[8 + ks];
            acc[0][0] = __builtin_amdgcn_mfma_f32_16x16x32_f16(a0, b0, acc[0][0], 0, 0, 0);
            acc[0][1] = __builtin_amdgcn_mfma_f32_16x16x32_f16(a0, b1, acc[0][1], 0, 0, 0);
            acc[1][0] = __builtin_amdgcn_mfma_f32_16x16x32_f16(a1, b0, acc[1][0], 0, 0, 0);
            acc[1][1] = __builtin_amdgcn_mfma_f32_16x16x32_f16(a1, b1, acc[1][1], 0, 0, 0);
        }
        // Epilogue: lane holds 4 consecutive feats of node (lane&15) per tile.
        #pragma unroll
        for (int ft = 0; ft < 2; ++ft) {
            #pragma unroll
            for (int nt = 0; nt < 2; ++nt) {
                int node = block0 + nt * 16 + (lane & 15);
                int f0 = wv * 32 + ft * 16 + ((lane >> 4) << 2);
                f4v r = acc[ft][nt];
                r.x = fmaxf(r.x, 0.f); r.y = fmaxf(r.y, 0.f);
                r.z = fmaxf(r.z, 0.f); r.w = fmaxf(r.w, 0.f);
                if (node < n_nodes) {
                    if constexpr (OUTFMT == 2) {
                        __builtin_nontemporal_store(r, (f4v*)(xout + (size_t)node * D + f0));
                    } else {
                        uint2 hu = {pkh(r.x, r.y), pkh(r.z, r.w)};
                        h16_out[(size_t)node * 32 + (f0 >> 2)] = hu;
                        if constexpr (OUTFMT == 0) {
                            unsigned u = 0;
                            u = __builtin_amdgcn_cvt_pk_fp8_f32(r.x * Q8_SCALE, r.y * Q8_SCALE, u, false);
                            u = __builtin_amdgcn_cvt_pk_fp8_f32(r.z * Q8_SCALE, r.w * Q8_SCALE, u, true);
                            q8_out[(size_t)node * 32 + (f0 >> 2)] = u;
                        }
                    }
                }
            }
        }
    }
}

extern "C" void kernel_launch(void* const* d_in, const int* in_sizes, int n_in,
                              void* d_out, int out_size, void* d_ws, size_t ws_size,
                              hipStream_t stream) {
    const float* x  = (const float*)d_in[0];
    const int*  edge = (const int*)d_in[1];
    const float* Wl = (const float*)d_in[2];
    const float* bl = (const float*)d_in[3];
    const float* Wr = (const float*)d_in[4];

    int N = in_sizes[0] / D;
    int E = in_sizes[1] / 2;
    int L = in_sizes[3] / D;   // 4
    const int* srcp = edge;
    const int* dstp = edge + E;

    char* w = (char*)d_ws;
    auto alloc = [&](size_t bytes) {
        char* p = w;
        w += (bytes + 255) & ~(size_t)255;
        return p;
    };
    int*   deg       = (int*)alloc((size_t)N * 4);
    int*   local_ex  = (int*)alloc((size_t)N * 4);
    int*   row_start = (int*)alloc((size_t)(N + 1) * 4);
    int*   cursor    = (int*)alloc((size_t)N * 4);
    int*   csr       = (int*)alloc((size_t)E * 4);
    float* invdeg    = (float*)alloc((size_t)N * 4);
    int*   blocksum  = (int*)alloc((size_t)1024 * 4);
    __half* wpack    = (__half*)alloc((size_t)L * 32768 * 2);   // 64KB/layer
    unsigned* q0     = (unsigned*)alloc((size_t)N * D);         // fp8 rows
    unsigned* q1     = (unsigned*)alloc((size_t)N * D);         // fp8 rows
    __half* h0       = (__half*)alloc((size_t)N * D * 2);       // fp16 rows
    __half* h1       = (__half*)alloc((size_t)N * D * 2);       // fp16 rows

    int nb1 = (N + 1023) / 1024;
    hipMemsetAsync(deg, 0, (size_t)N * 4, stream);
    hist_kernel<<<(E + 255) / 256, 256, 0, stream>>>(dstp, deg, E);
    scan1_kernel<<<nb1, 1024, 0, stream>>>(deg, local_ex, blocksum, N);
    scan2_kernel<<<1, 1024, 0, stream>>>(blocksum, nb1);
    scan3_kernel<<<nb1, 1024, 0, stream>>>(deg, local_ex, blocksum, row_start,
                                           cursor, invdeg, N, E);
    int npx = (N + 7) / 8;
    scatter_kernel<<<2048, 256, 0, stream>>>(srcp, dstp, cursor, csr, E, npx);
    int tp = L * 4096;
    prepack_w<<<(tp + 255) / 256, 256, 0, stream>>>(Wl, Wr, wpack, tp);
    int t4 = N * (D / 4);
    x_to_shadow<<<(t4 + 255) / 256, 256, 0, stream>>>(x, q0, (uint2*)h0, t4);

    float* out = (float*)d_out;
    int nbl = (N + TM - 1) / TM;

    // l0: gather fp8 q0, X-fill h0 -> write q1 + h1
    sage_layer_mfma<0, 0><<<nbl, 256, 0, stream>>>(h0, q0, nullptr, q1, (uint2*)h1,
                                                   row_start, csr, invdeg,
                                                   wpack + 0 * 32768, bl + 0 * D, N);
    // l1: gather fp8 q1, X-fill h1 -> write q0 + h0
    sage_layer_mfma<0, 0><<<nbl, 256, 0, stream>>>(h1, q1, nullptr, q0, (uint2*)h0,
                                                   row_start, csr, invdeg,
                                                   wpack + 1 * 32768, bl + 1 * D, N);
    // l2: gather fp8 q0, X-fill h0 -> write h1 only (l3 gathers+X-fills fp16)
    sage_layer_mfma<0, 1><<<nbl, 256, 0, stream>>>(h0, q0, nullptr, nullptr, (uint2*)h1,
                                                   row_start, csr, invdeg,
                                                   wpack + 2 * 32768, bl + 2 * D, N);
    // l3: gather fp16 h1, X-fill h1 -> write fp32 out (final)
    sage_layer_mfma<1, 2><<<nbl, 256, 0, stream>>>(h1, h1, out, nullptr, nullptr,
                                                   row_start, csr, invdeg,
                                                   wpack + 3 * 32768, bl + 3 * D, N);
}

// Round 12
// 450.373 us; speedup vs baseline: 1.2105x; 1.0342x over previous
//
#include <hip/hip_runtime.h>
#include <hip/hip_fp16.h>

#define D 128
#define TM 32    // nodes per block
#define AHP 264  // MFMA A-tile halves/row: 528B, +16B pad -> <=2-way bank alias

typedef float f4v __attribute__((ext_vector_type(4)));
typedef float f2v __attribute__((ext_vector_type(2)));
typedef _Float16 h8v __attribute__((ext_vector_type(8)));

#define Q8_SCALE 16.0f      // fp8 storage scale: |act|*16 << 448 (e4m3 max)
#define Q8_INV   0.0625f

static __device__ __forceinline__ unsigned pkh(float a, float b) {
    __half2 h = __float22half2_rn(make_float2(a, b));
    return *(unsigned*)&h;
}

// ---------------- CSR build ----------------

__global__ void hist_kernel(const int* __restrict__ dst, int* __restrict__ deg, int E) {
    int i = blockIdx.x * blockDim.x + threadIdx.x;
    if (i < E) {
        int d = __builtin_nontemporal_load(dst + i);
        atomicAdd(&deg[d], 1);
    }
}

__global__ void scan1_kernel(const int* __restrict__ deg, int* __restrict__ local_excl,
                             int* __restrict__ blocksum, int n) {
    __shared__ int tmp[1024];
    int i = blockIdx.x * 1024 + threadIdx.x;
    int v = (i < n) ? deg[i] : 0;
    tmp[threadIdx.x] = v;
    __syncthreads();
    for (int off = 1; off < 1024; off <<= 1) {
        int t = 0;
        if (threadIdx.x >= off) t = tmp[threadIdx.x - off];
        __syncthreads();
        if (threadIdx.x >= off) tmp[threadIdx.x] += t;
        __syncthreads();
    }
    int incl = tmp[threadIdx.x];
    if (i < n) local_excl[i] = incl - v;
    if (threadIdx.x == 1023) blocksum[blockIdx.x] = tmp[1023];
}

__global__ void scan2_kernel(int* __restrict__ blocksum, int nb) {
    __shared__ int tmp[1024];
    int v = (threadIdx.x < nb) ? blocksum[threadIdx.x] : 0;
    tmp[threadIdx.x] = v;
    __syncthreads();
    for (int off = 1; off < 1024; off <<= 1) {
        int t = 0;
        if (threadIdx.x >= off) t = tmp[threadIdx.x - off];
        __syncthreads();
        if (threadIdx.x >= off) tmp[threadIdx.x] += t;
        __syncthreads();
    }
    if (threadIdx.x < nb) blocksum[threadIdx.x] = tmp[threadIdx.x] - v;  // exclusive
}

__global__ void scan3_kernel(const int* __restrict__ deg, const int* __restrict__ local_excl,
                             const int* __restrict__ blocksum, int* __restrict__ row_start,
                             int* __restrict__ cursor, float* __restrict__ inv_deg,
                             int n, int n_edges) {
    int i = blockIdx.x * 1024 + threadIdx.x;
    if (i < n) {
        int rs = local_excl[i] + blocksum[blockIdx.x];
        row_start[i] = rs;
        cursor[i]    = rs;
        inv_deg[i]   = 1.0f / fmaxf((float)deg[i], 1.0f);
    }
    if (i == 0) row_start[n] = n_edges;
}

// csr[] holds BYTE offsets of the fp8 source row (src * 128).
// r18: XCD-affine scatter (slot x = blockIdx&7 -> dst range x only).
// r21: nt loads on the dst/src streams. r20 post-mortem: scatter WRITE was
// still 72MB (csr logical = 6.4MB) because each slot grid-strides the whole
// 6.4MB dst array through its 4MB L2, evicting partially-filled csr lines
// repeatedly. nt keeps the edge streams out of L2 so dirty csr lines
// survive until fully coalesced.
__global__ void scatter_kernel(const int* __restrict__ src, const int* __restrict__ dst,
                               int* __restrict__ cursor, int* __restrict__ csr,
                               int E, int npx) {
    int x  = blockIdx.x & 7;
    int lo = x * npx, hi = lo + npx;
    int stride = (gridDim.x >> 3) * blockDim.x;
    for (int i = (blockIdx.x >> 3) * blockDim.x + threadIdx.x; i < E; i += stride) {
        int d = __builtin_nontemporal_load(dst + i);
        if (d >= lo && d < hi) {
            int s = __builtin_nontemporal_load(src + i);
            int p = atomicAdd(&cursor[d], 1);
            csr[p] = s << 7;
        }
    }
}

// ---------------- MFMA weight prepack ----------------
// Fragment-order fp16 pack for mfma_f32_16x16x32_f16, swapped-operand use:
// A-operand = weight tile, lane l holds row f = ft*16+(l&15),
// k = ks*32 + (l>>4)*8 + j (j=0..7). K-concat: ks 0..3 -> Wl (agg path),
// ks 4..7 -> Wr (x path). One fragment = 64 consecutive uint4 = 1KB
// contiguous -> frag loads in the layer kernel are coalesced dwordx4.
__global__ void prepack_w(const float* __restrict__ Wl, const float* __restrict__ Wr,
                          __half* __restrict__ wpack, int total) {
    int t = blockIdx.x * blockDim.x + threadIdx.x;   // ((l*8+ft)*8+ks)*64+lane
    if (t >= total) return;
    int lane = t & 63;
    int ks   = (t >> 6) & 7;
    int ft   = (t >> 9) & 7;
    int l    = t >> 12;
    int f = ft * 16 + (lane & 15);
    int k = (ks & 3) * 32 + ((lane >> 4) << 3);
    const float* W = (ks < 4) ? Wl : Wr;
    const float* src = W + ((size_t)l << 14) + ((size_t)f << 7) + k;
    float4 v0 = *(const float4*)src;
    float4 v1 = *(const float4*)(src + 4);
    uint4 u = {pkh(v0.x, v0.y), pkh(v0.z, v0.w), pkh(v1.x, v1.y), pkh(v1.z, v1.w)};
    ((uint4*)wpack)[t] = u;
}

// ---------------- initial fp32 -> fp8 + fp16 shadow copies ----------------

__global__ void x_to_shadow(const float* __restrict__ x, unsigned* __restrict__ xq,
                            uint2* __restrict__ xh, int total4) {
    int i = blockIdx.x * blockDim.x + threadIdx.x;
    if (i < total4) {
        float4 v = ((const float4*)x)[i];
        unsigned u = 0;
        u = __builtin_amdgcn_cvt_pk_fp8_f32(v.x * Q8_SCALE, v.y * Q8_SCALE, u, false);
        u = __builtin_amdgcn_cvt_pk_fp8_f32(v.z * Q8_SCALE, v.w * Q8_SCALE, u, true);
        xq[i] = u;
        uint2 h = {pkh(v.x, v.y), pkh(v.z, v.w)};
        xh[i] = h;
    }
}

// ---------------- gather helpers ----------------

#define ACC16Q(V) {                                                          \
    f2v a0_ = __builtin_amdgcn_cvt_pk_f32_fp8((int)(V).x, false);            \
    f2v a1_ = __builtin_amdgcn_cvt_pk_f32_fp8((int)(V).x, true);             \
    f2v b0_ = __builtin_amdgcn_cvt_pk_f32_fp8((int)(V).y, false);            \
    f2v b1_ = __builtin_amdgcn_cvt_pk_f32_fp8((int)(V).y, true);             \
    f2v c0_ = __builtin_amdgcn_cvt_pk_f32_fp8((int)(V).z, false);            \
    f2v c1_ = __builtin_amdgcn_cvt_pk_f32_fp8((int)(V).z, true);             \
    f2v d0_ = __builtin_amdgcn_cvt_pk_f32_fp8((int)(V).w, false);            \
    f2v d1_ = __builtin_amdgcn_cvt_pk_f32_fp8((int)(V).w, true);             \
    s0.x += a0_.x; s0.y += a0_.y; s0.z += a1_.x; s0.w += a1_.y;              \
    s1.x += b0_.x; s1.y += b0_.y; s1.z += b1_.x; s1.w += b1_.y;              \
    s2.x += c0_.x; s2.y += c0_.y; s2.z += c1_.x; s2.w += c1_.y;              \
    s3.x += d0_.x; s3.y += d0_.y; s3.z += d1_.x; s3.w += d1_.y; }

#define ACC8(V) { const __half2* hp_ = (const __half2*)&(V);                 \
    float2 f0_ = __half22float2(hp_[0]); float2 f1_ = __half22float2(hp_[1]);\
    float2 f2_ = __half22float2(hp_[2]); float2 f3_ = __half22float2(hp_[3]);\
    sA.x += f0_.x; sA.y += f0_.y; sA.z += f1_.x; sA.w += f1_.y;              \
    sB.x += f2_.x; sB.y += f2_.y; sB.z += f3_.x; sB.w += f3_.y; }

// ---------------- MFMA fused SAGE layer ----------------
// r21: epilogue LDS-bounce. r20 post-mortem: layer WRITE_SIZE was 70MB vs
// 38.4MB logical -- the per-lane epilogue stores write 8B to 16 different
// lines per instruction (lane = node, 256B stride); under gather L2
// pressure, partially-written shadow lines evict early -> ~1.8x write
// amplification. Fix: after the MFMAs, sync, park results in the now-dead
// A-tile LDS, sync, write out row-contiguous uint4 bursts (one full line
// per 4 consecutive lanes) -> each line produced by one coalesced burst.
// Bounce layout per row (528B): fp16 row bytes 0..255, fp8 row 256..383;
// OUTFMT==2 uses bytes 0..511 as the fp32 row.
// INFMT: 0 = gather fp8 rows (128B), 1 = gather fp16 rows (256B).
// OUTFMT: 0 = write fp8+fp16 shadows, 1 = fp16 shadow only, 2 = fp32 final.
template<int INFMT, int OUTFMT>
__global__ __launch_bounds__(256, 4)
void sage_layer_mfma(const __half* __restrict__ xh_in,
                     const void* __restrict__ xq_in,
                     float* __restrict__ xout,
                     unsigned* __restrict__ q8_out,
                     uint2* __restrict__ h16_out,
                     const int* __restrict__ row_start, const int* __restrict__ csr,
                     const float* __restrict__ inv_deg,
                     const __half* __restrict__ wpack,
                     const float* __restrict__ bl, int n_nodes) {
    __shared__ __align__(16) __half Ah[TM][AHP];
    int block0 = blockIdx.x * TM;
    int tid = threadIdx.x;
    int lane = tid & 63;
    int wv   = tid >> 6;

    // X-fill: fp16 shadow rows -> columns 128..255 of A-tile (pure copy,
    // cache-hot source: written by the previous layer).
    {
        int row = tid >> 3;          // 0..31
        int seg = tid & 7;           // 16 halves per thread
        int nn = block0 + row;
        uint4 a = {0,0,0,0}, b = a;
        if (nn < n_nodes) {
            const uint4* hp = (const uint4*)(xh_in + (size_t)nn * D) + seg * 2;
            a = hp[0];
            b = hp[1];
        }
        uint4* dst = (uint4*)&Ah[row][128 + seg * 16];
        dst[0] = a; dst[1] = b;
    }

    // Phase A: gather -> fp32 acc -> fp16 into columns 0..127 of A-tile.
    if constexpr (INFMT == 0) {
        // fp8: 8-lane group per node, 32 concurrent nodes, 4-deep pipeline.
        int g   = tid >> 3;       // 0..31
        int sub = tid & 7;
        int n = block0 + g;
        float4 s0 = {0,0,0,0}, s1 = {0,0,0,0}, s2 = {0,0,0,0}, s3 = {0,0,0,0};
        float idg = 1.f;
        int e0 = 0, e1 = 0;
        if (n < n_nodes) {
            e0 = row_start[n];
            e1 = row_start[n + 1];
            idg = inv_deg[n];
        }
        int e = e0;
        if (e < e1) {
            int last = e1 - 1;
            const char* qbase = (const char*)xq_in;
            int laneoff = sub * 16;
            int i0 = csr[min(e,     last)];
            int i1 = csr[min(e + 1, last)];
            int i2 = csr[min(e + 2, last)];
            int i3 = csr[min(e + 3, last)];
            while (1) {
                uint4 v0 = *(const uint4*)(qbase + (size_t)(i0 + laneoff));
                uint4 v1 = *(const uint4*)(qbase + (size_t)(i1 + laneoff));
                uint4 v2 = *(const uint4*)(qbase + (size_t)(i2 + laneoff));
                uint4 v3 = *(const uint4*)(qbase + (size_t)(i3 + laneoff));
                int en = e + 4;
                bool more = en < e1;
                int p0, p1, p2, p3;
                if (more) {
                    p0 = csr[min(en,     last)];
                    p1 = csr[min(en + 1, last)];
                    p2 = csr[min(en + 2, last)];
                    p3 = csr[min(en + 3, last)];
                }
                ACC16Q(v0)
                if (e + 1 <= last) ACC16Q(v1)
                if (e + 2 <= last) ACC16Q(v2)
                if (e + 3 <= last) ACC16Q(v3)
                if (!more) break;
                e = en;
                i0 = p0; i1 = p1; i2 = p2; i3 = p3;
            }
        }
        float sc = idg * Q8_INV;
        uint4 ua = {pkh(s0.x*sc,s0.y*sc), pkh(s0.z*sc,s0.w*sc),
                    pkh(s1.x*sc,s1.y*sc), pkh(s1.z*sc,s1.w*sc)};
        uint4 ub = {pkh(s2.x*sc,s2.y*sc), pkh(s2.z*sc,s2.w*sc),
                    pkh(s3.x*sc,s3.y*sc), pkh(s3.z*sc,s3.w*sc)};
        uint4* dst = (uint4*)&Ah[g][sub * 16];
        dst[0] = ua; dst[1] = ub;
    } else {
        // fp16: 16-lane group per node, 2 sequential nodes per group.
        int g   = tid >> 4;       // 0..15
        int sub = tid & 15;
        const char* hbase = (const char*)xq_in;
        int laneoff = sub * 16;   // 16B per lane within 256B fp16 row
        for (int t = 0; t < 2; ++t) {
            int j = g + t * 16;
            int n = block0 + j;
            float4 sA = {0,0,0,0}, sB = {0,0,0,0};
            float idg = 1.f;
            int e0 = 0, e1 = 0;
            if (n < n_nodes) {
                e0 = row_start[n];
                e1 = row_start[n + 1];
                idg = inv_deg[n];
            }
            int e = e0;
            if (e < e1) {
                int last = e1 - 1;
                int i0 = csr[min(e,     last)] << 1;
                int i1 = csr[min(e + 1, last)] << 1;
                int i2 = csr[min(e + 2, last)] << 1;
                int i3 = csr[min(e + 3, last)] << 1;
                while (1) {
                    float4 v0 = *(const float4*)(hbase + (size_t)(i0 + laneoff));
                    float4 v1 = *(const float4*)(hbase + (size_t)(i1 + laneoff));
                    float4 v2 = *(const float4*)(hbase + (size_t)(i2 + laneoff));
                    float4 v3 = *(const float4*)(hbase + (size_t)(i3 + laneoff));
                    int en = e + 4;
                    bool more = en < e1;
                    int p0, p1, p2, p3;
                    if (more) {
                        p0 = csr[min(en,     last)] << 1;
                        p1 = csr[min(en + 1, last)] << 1;
                        p2 = csr[min(en + 2, last)] << 1;
                        p3 = csr[min(en + 3, last)] << 1;
                    }
                    ACC8(v0)
                    if (e + 1 <= last) ACC8(v1)
                    if (e + 2 <= last) ACC8(v2)
                    if (e + 3 <= last) ACC8(v3)
                    if (!more) break;
                    e = en;
                    i0 = p0; i1 = p1; i2 = p2; i3 = p3;
                }
            }
            uint4 u = {pkh(sA.x*idg, sA.y*idg), pkh(sA.z*idg, sA.w*idg),
                       pkh(sB.x*idg, sB.y*idg), pkh(sB.z*idg, sB.w*idg)};
            *(uint4*)&Ah[j][sub * 8] = u;
        }
    }

    // Preload this wave's 16 weight fragments (2 f-tiles x 8 k-steps),
    // each a unique-data coalesced 1KB dwordx4. L2-hot after block 0.
    uint4 wf[16];
    {
        const uint4* wp = (const uint4*)wpack;
        #pragma unroll
        for (int i = 0; i < 16; ++i) {
            int ft = wv * 2 + (i >> 3);
            int ks = i & 7;
            wf[i] = wp[(size_t)(ft * 8 + ks) * 64 + lane];
        }
    }

    __syncthreads();

    // Phase B: wave wv owns feature tiles {2wv, 2wv+1} x node tiles {0,1}.
    f4v acc[2][2];
    {
        #pragma unroll
        for (int ft = 0; ft < 2; ++ft) {
            int f0 = wv * 32 + ft * 16 + ((lane >> 4) << 2);
            f4v bv = *(const f4v*)(bl + f0);
            acc[ft][0] = bv;
            acc[ft][1] = bv;
        }
        #pragma unroll
        for (int ks = 0; ks < 8; ++ks) {
            int koff = ks * 32 + ((lane >> 4) << 3);
            h8v b0 = *(const h8v*)&Ah[lane & 15][koff];
            h8v b1 = *(const h8v*)&Ah[16 + (lane & 15)][koff];
            h8v a0 = *(const h8v*)&wf[ks];
            h8v a1 = *(const h8v*)&wf[8 + ks];
            acc[0][0] = __builtin_amdgcn_mfma_f32_16x16x32_f16(a0, b0, acc[0][0], 0, 0, 0);
            acc[0][1] = __builtin_amdgcn_mfma_f32_16x16x32_f16(a0, b1, acc[0][1], 0, 0, 0);
            acc[1][0] = __builtin_amdgcn_mfma_f32_16x16x32_f16(a1, b0, acc[1][0], 0, 0, 0);
            acc[1][1] = __builtin_amdgcn_mfma_f32_16x16x32_f16(a1, b1, acc[1][1], 0, 0, 0);
        }
    }

    // Epilogue stage 1: relu + convert, park in the now-dead A-tile LDS.
    __syncthreads();   // all waves done reading Ah
    {
        #pragma unroll
        for (int ft = 0; ft < 2; ++ft) {
            #pragma unroll
            for (int nt = 0; nt < 2; ++nt) {
                int j  = nt * 16 + (lane & 15);             // local node row
                int f0 = wv * 32 + ft * 16 + ((lane >> 4) << 2);
                f4v r = acc[ft][nt];
                r.x = fmaxf(r.x, 0.f); r.y = fmaxf(r.y, 0.f);
                r.z = fmaxf(r.z, 0.f); r.w = fmaxf(r.w, 0.f);
                char* rowp = (char*)&Ah[j][0];
                if constexpr (OUTFMT == 2) {
                    *(f4v*)(rowp + (size_t)f0 * 4) = r;     // fp32 row 0..511
                } else {
                    uint2 hu = {pkh(r.x, r.y), pkh(r.z, r.w)};
                    *(uint2*)(rowp + (size_t)f0 * 2) = hu;  // fp16 row 0..255
                    if constexpr (OUTFMT == 0) {
                        unsigned u = 0;
                        u = __builtin_amdgcn_cvt_pk_fp8_f32(r.x * Q8_SCALE, r.y * Q8_SCALE, u, false);
                        u = __builtin_amdgcn_cvt_pk_fp8_f32(r.z * Q8_SCALE, r.w * Q8_SCALE, u, true);
                        *(unsigned*)(rowp + 256 + f0) = u;  // fp8 row 256..383
                    }
                }
            }
        }
    }
    __syncthreads();

    // Epilogue stage 2: row-contiguous coalesced write-out (full lines).
    if constexpr (OUTFMT == 2) {
        #pragma unroll
        for (int k = 0; k < 4; ++k) {
            int idx = tid + k * 256;         // 1024 uint4s
            int row = idx >> 5, c4 = idx & 31;
            int node = block0 + row;
            if (node < n_nodes) {
                f4v v = *(const f4v*)((char*)&Ah[row][0] + c4 * 16);
                __builtin_nontemporal_store(v, (f4v*)(xout + (size_t)node * D) + c4);
            }
        }
    } else {
        #pragma unroll
        for (int k = 0; k < 2; ++k) {
            int idx = tid + k * 256;         // 512 uint4s
            int row = idx >> 4, c4 = idx & 15;
            int node = block0 + row;
            if (node < n_nodes) {
                uint4 v = *(const uint4*)((char*)&Ah[row][0] + c4 * 16);
                ((uint4*)h16_out)[(size_t)node * 16 + c4] = v;
            }
        }
        if constexpr (OUTFMT == 0) {
            int row = tid >> 3, c4 = tid & 7;   // 256 uint4s
            int node = block0 + row;
            if (node < n_nodes) {
                uint4 v = *(const uint4*)((char*)&Ah[row][0] + 256 + c4 * 16);
                ((uint4*)q8_out)[(size_t)node * 8 + c4] = v;
            }
        }
    }
}

extern "C" void kernel_launch(void* const* d_in, const int* in_sizes, int n_in,
                              void* d_out, int out_size, void* d_ws, size_t ws_size,
                              hipStream_t stream) {
    const float* x  = (const float*)d_in[0];
    const int*  edge = (const int*)d_in[1];
    const float* Wl = (const float*)d_in[2];
    const float* bl = (const float*)d_in[3];
    const float* Wr = (const float*)d_in[4];

    int N = in_sizes[0] / D;
    int E = in_sizes[1] / 2;
    int L = in_sizes[3] / D;   // 4
    const int* srcp = edge;
    const int* dstp = edge + E;

    char* w = (char*)d_ws;
    auto alloc = [&](size_t bytes) {
        char* p = w;
        w += (bytes + 255) & ~(size_t)255;
        return p;
    };
    int*   deg       = (int*)alloc((size_t)N * 4);
    int*   local_ex  = (int*)alloc((size_t)N * 4);
    int*   row_start = (int*)alloc((size_t)(N + 1) * 4);
    int*   cursor    = (int*)alloc((size_t)N * 4);
    int*   csr       = (int*)alloc((size_t)E * 4);
    float* invdeg    = (float*)alloc((size_t)N * 4);
    int*   blocksum  = (int*)alloc((size_t)1024 * 4);
    __half* wpack    = (__half*)alloc((size_t)L * 32768 * 2);   // 64KB/layer
    unsigned* q0     = (unsigned*)alloc((size_t)N * D);         // fp8 rows
    unsigned* q1     = (unsigned*)alloc((size_t)N * D);         // fp8 rows
    __half* h0       = (__half*)alloc((size_t)N * D * 2);       // fp16 rows
    __half* h1       = (__half*)alloc((size_t)N * D * 2);       // fp16 rows

    int nb1 = (N + 1023) / 1024;
    hipMemsetAsync(deg, 0, (size_t)N * 4, stream);
    hist_kernel<<<(E + 255) / 256, 256, 0, stream>>>(dstp, deg, E);
    scan1_kernel<<<nb1, 1024, 0, stream>>>(deg, local_ex, blocksum, N);
    scan2_kernel<<<1, 1024, 0, stream>>>(blocksum, nb1);
    scan3_kernel<<<nb1, 1024, 0, stream>>>(deg, local_ex, blocksum, row_start,
                                           cursor, invdeg, N, E);
    int npx = (N + 7) / 8;
    scatter_kernel<<<2048, 256, 0, stream>>>(srcp, dstp, cursor, csr, E, npx);
    int tp = L * 4096;
    prepack_w<<<(tp + 255) / 256, 256, 0, stream>>>(Wl, Wr, wpack, tp);
    int t4 = N * (D / 4);
    x_to_shadow<<<(t4 + 255) / 256, 256, 0, stream>>>(x, q0, (uint2*)h0, t4);

    float* out = (float*)d_out;
    int nbl = (N + TM - 1) / TM;

    // l0: gather fp8 q0, X-fill h0 -> write q1 + h1
    sage_layer_mfma<0, 0><<<nbl, 256, 0, stream>>>(h0, q0, nullptr, q1, (uint2*)h1,
                                                   row_start, csr, invdeg,
                                                   wpack + 0 * 32768, bl + 0 * D, N);
    // l1: gather fp8 q1, X-fill h1 -> write q0 + h0
    sage_layer_mfma<0, 0><<<nbl, 256, 0, stream>>>(h1, q1, nullptr, q0, (uint2*)h0,
                                                   row_start, csr, invdeg,
                                                   wpack + 1 * 32768, bl + 1 * D, N);
    // l2: gather fp8 q0, X-fill h0 -> write h1 only (l3 gathers+X-fills fp16)
    sage_layer_mfma<0, 1><<<nbl, 256, 0, stream>>>(h0, q0, nullptr, nullptr, (uint2*)h1,
                                                   row_start, csr, invdeg,
                                                   wpack + 2 * 32768, bl + 2 * D, N);
    // l3: gather fp16 h1, X-fill h1 -> write fp32 out (final)
    sage_layer_mfma<1, 2><<<nbl, 256, 0, stream>>>(h1, h1, out, nullptr, nullptr,
                                                   row_start, csr, invdeg,
                                                   wpack + 3 * 32768, bl + 3 * D, N);
}